// Round 18
// baseline (222.441 us; speedup 1.0000x reference)
//
#include <hip/hip_runtime.h>
#include <hip/hip_bf16.h>
#include <stdint.h>

#define H_   12
#define KV_  2
#define D_   128
#define HID_ 1536
#define B_   4
#define S_   2048
#define T_   (B_*S_)

typedef __attribute__((ext_vector_type(8))) short  bf16x8;
typedef __attribute__((ext_vector_type(4))) float  f32x4;

__device__ __forceinline__ ushort f2bf(float f) {
  union { float f; uint32_t u; } v; v.f = f;
  uint32_t u = v.u;
  return (ushort)((u + 0x7fffu + ((u >> 16) & 1u)) >> 16);  // RNE
}
__device__ __forceinline__ float bf2f(ushort u) {
  union { uint32_t u; float f; } v; v.u = ((uint32_t)u) << 16;
  return v.f;
}
__device__ __forceinline__ uint32_t cvtpk_bf16(float lo, float hi) {
  uint32_t r;
  asm("v_cvt_pk_bf16_f32 %0, %1, %2" : "=v"(r) : "v"(lo), "v"(hi));
  return r;
}

__device__ __forceinline__ void gload_lds16(const void* g, void* l) {
  __builtin_amdgcn_global_load_lds(
      (const __attribute__((address_space(1))) uint32_t*)g,
      (__attribute__((address_space(3))) uint32_t*)l, 16, 0, 0);
}

// ---------------- transpose + convert, dual-source: W (K,N) fp32 -> Wt (N,K) bf16 ----------------
__global__ __launch_bounds__(256) void transpose_cvt2(const float* __restrict__ W0,
                                                      ushort* __restrict__ Wt0,
                                                      const float* __restrict__ W1,
                                                      ushort* __restrict__ Wt1,
                                                      int K, int N) {
  __shared__ float tile[32][33];
  const float* W  = blockIdx.z ? W1  : W0;
  ushort*      Wt = blockIdx.z ? Wt1 : Wt0;
  int k0 = blockIdx.x * 32, n0 = blockIdx.y * 32;
  int tx = threadIdx.x & 31, ty = threadIdx.x >> 5;  // ty 0..7
#pragma unroll
  for (int i = 0; i < 32; i += 8)
    tile[ty + i][tx] = W[(long)(k0 + ty + i) * N + n0 + tx];
  __syncthreads();
#pragma unroll
  for (int i = 0; i < 32; i += 8)
    Wt[(long)(n0 + ty + i) * K + k0 + tx] = f2bf(tile[tx][ty + i]);
}

// ------- GEMM 128x128, BK=64, 4 waves, explicit double-buffer (gemm256's schedule at 128 tile) ----
// STAGE(kt+1) issued BEFORE computing kt; one __syncthreads per K-tile. LDS 64KB -> 2 blocks/CU.
// T2 swizzle: linear gload_lds dest + inverse-swizzled global SOURCE col (slot^(r&7)) +
// swizzled READ (^ (l15&7)<<4). Same involution as the proven gemm256.
template <int OUT_F32>
__global__ __launch_bounds__(256) void gemm_bt64(const ushort* __restrict__ A,
                                                 const ushort* __restrict__ Bt,
                                                 void* __restrict__ Cv,
                                                 int M, int N, int K, int lda) {
  __shared__ ushort lA[2][128 * 64];
  __shared__ ushort lB[2][128 * 64];
  const int tid = threadIdx.x, lane = tid & 63, w = tid >> 6;
  const int wr = w >> 1, wc = w & 1;
  const int l15 = lane & 15, lh = lane >> 4;
  const long m0 = (long)blockIdx.x * 128, n0 = (long)blockIdx.y * 128;
  const ushort* Ab = A + m0 * lda;
  const ushort* Bb = Bt + n0 * K;
  const int swz = (l15 & 7) << 4;

  f32x4 acc[4][4] = {};
  const int NT = K / 64;

#define STG128(KT, PB) do {                                                        \
  const int k0s = (KT) * 64;                                                       \
  _Pragma("unroll") for (int it = 0; it < 4; ++it) {                               \
    int ch = it * 256 + tid; int r = ch >> 3, s = ch & 7;                          \
    int cb = it * 256 + (tid & 192);                                               \
    gload_lds16(Ab + (long)r * lda + k0s + ((s ^ (r & 7)) * 8), &lA[PB][cb * 8]);  \
  }                                                                                \
  _Pragma("unroll") for (int it = 0; it < 4; ++it) {                               \
    int ch = it * 256 + tid; int r = ch >> 3, s = ch & 7;                          \
    int cb = it * 256 + (tid & 192);                                               \
    gload_lds16(Bb + (long)r * K + k0s + ((s ^ (r & 7)) * 8), &lB[PB][cb * 8]);    \
  }                                                                                \
} while (0)

  STG128(0, 0);
  __syncthreads();                       // tile 0 resident + visible
  int p = 0;
  for (int kt = 0; kt < NT; ++kt) {
    if (kt + 1 < NT) STG128(kt + 1, p ^ 1);   // in flight under this tile's compute
    const char* cA = (const char*)&lA[p][0];
    const char* cB = (const char*)&lB[p][0];
    bf16x8 bfr[4][2];
#pragma unroll
    for (int j = 0; j < 4; ++j)
#pragma unroll
      for (int kk = 0; kk < 2; ++kk)
        bfr[j][kk] = *(const bf16x8*)(cB + (wc * 64 + j * 16 + l15) * 128 + ((kk * 64 + lh * 16) ^ swz));
    __builtin_amdgcn_s_setprio(1);
#pragma unroll
    for (int i = 0; i < 4; ++i) {
      const int ra = (wr * 64 + i * 16 + l15) * 128;
      bf16x8 af0 = *(const bf16x8*)(cA + ra + ((lh * 16) ^ swz));
      bf16x8 af1 = *(const bf16x8*)(cA + ra + ((64 + lh * 16) ^ swz));
#pragma unroll
      for (int j = 0; j < 4; ++j) {
        acc[i][j] = __builtin_amdgcn_mfma_f32_16x16x32_bf16(af0, bfr[j][0], acc[i][j], 0, 0, 0);
        acc[i][j] = __builtin_amdgcn_mfma_f32_16x16x32_bf16(af1, bfr[j][1], acc[i][j], 0, 0, 0);
      }
    }
    __builtin_amdgcn_s_setprio(0);
    __syncthreads();                     // drains stage loads + visibility
    p ^= 1;
  }
#undef STG128
#pragma unroll
  for (int i = 0; i < 4; ++i) {
#pragma unroll
    for (int q = 0; q < 4; ++q) {
      long row = m0 + wr * 64 + i * 16 + lh * 4 + q;
#pragma unroll
      for (int j = 0; j < 4; ++j) {
        long col = n0 + wc * 64 + j * 16 + l15;
        float v = acc[i][j][q];
        if (OUT_F32) ((float*)Cv)[row * N + col] = v;
        else         ((ushort*)Cv)[row * N + col] = f2bf(v);
      }
    }
  }
}

// ------- GEMM 256x256 with FUSED fp32->bf16 A conversion (reg-staged A, gload_lds B) -------
__global__ __launch_bounds__(512) void gemm256f(const float* __restrict__ A32,
                                                const ushort* __restrict__ Bt,
                                                ushort* __restrict__ Cv,
                                                int M, int N, int K, int lda) {
  __shared__ ushort lA[2][256 * 64];
  __shared__ ushort lB[2][256 * 64];
  const int tid = threadIdx.x, lane = tid & 63;
  const int w = tid >> 6;
  const int l15 = lane & 15, lh = lane >> 4;
  const int wr = w >> 2, wc = w & 3;
  const long m0 = (long)blockIdx.x * 256, n0 = (long)blockIdx.y * 256;
  const float*  Ab = A32 + m0 * lda;
  const ushort* Bb = Bt + n0 * K;
  const int swz = (l15 & 7) << 4;

  f32x4 acc[8][4] = {};
  const int NT = K / 64;
  float4 areg[4][2];

#define ALOAD(KT) do {                                                        \
  const int k0s = (KT) * 64;                                                  \
  _Pragma("unroll") for (int it = 0; it < 4; ++it) {                          \
    int ch = it * 512 + tid; int r = ch >> 3, s = ch & 7;                     \
    const float* src = Ab + (long)r * lda + k0s + ((s ^ (r & 7)) * 8);        \
    areg[it][0] = *(const float4*)src;                                        \
    areg[it][1] = *(const float4*)(src + 4);                                  \
  }                                                                           \
} while (0)
#define AWRITE(PB) do {                                                       \
  _Pragma("unroll") for (int it = 0; it < 4; ++it) {                          \
    int ch = it * 512 + tid; int r = ch >> 3, s = ch & 7;                     \
    uint32_t pk0 = cvtpk_bf16(areg[it][0].x, areg[it][0].y);                  \
    uint32_t pk1 = cvtpk_bf16(areg[it][0].z, areg[it][0].w);                  \
    uint32_t pk2 = cvtpk_bf16(areg[it][1].x, areg[it][1].y);                  \
    uint32_t pk3 = cvtpk_bf16(areg[it][1].z, areg[it][1].w);                  \
    uint4 pk = make_uint4(pk0, pk1, pk2, pk3);                                \
    *(uint4*)&lA[PB][r * 64 + s * 8] = pk;                                    \
  }                                                                           \
} while (0)
#define BSTAGE(KT, PB) do {                                                   \
  const int k0s = (KT) * 64;                                                  \
  _Pragma("unroll") for (int it = 0; it < 4; ++it) {                          \
    int ch = it * 512 + tid; int r = ch >> 3, s = ch & 7;                     \
    int cb = it * 512 + (tid & 448);                                          \
    gload_lds16(Bb + (long)r * K + k0s + ((s ^ (r & 7)) * 8), &lB[PB][cb * 8]); \
  }                                                                           \
} while (0)

  ALOAD(0);
  BSTAGE(0, 0);
  AWRITE(0);
  __syncthreads();
  int p = 0;
  for (int kt = 0; kt < NT; ++kt) {
    if (kt + 1 < NT) { ALOAD(kt + 1); BSTAGE(kt + 1, p ^ 1); }
    const char* cA = (const char*)&lA[p][0];
    const char* cB = (const char*)&lB[p][0];
    bf16x8 bf[4][2];
#pragma unroll
    for (int fj = 0; fj < 4; ++fj)
#pragma unroll
      for (int kk = 0; kk < 2; ++kk)
        bf[fj][kk] = *(const bf16x8*)(cB + (wc * 64 + fj * 16 + l15) * 128 + ((kk * 64 + lh * 16) ^ swz));
    __builtin_amdgcn_s_setprio(1);
#pragma unroll
    for (int fi = 0; fi < 8; ++fi) {
      const int ra = (wr * 128 + fi * 16 + l15) * 128;
      bf16x8 af0 = *(const bf16x8*)(cA + ra + ((lh * 16) ^ swz));
      bf16x8 af1 = *(const bf16x8*)(cA + ra + ((64 + lh * 16) ^ swz));
#pragma unroll
      for (int fj = 0; fj < 4; ++fj) {
        acc[fi][fj] = __builtin_amdgcn_mfma_f32_16x16x32_bf16(af0, bf[fj][0], acc[fi][fj], 0, 0, 0);
        acc[fi][fj] = __builtin_amdgcn_mfma_f32_16x16x32_bf16(af1, bf[fj][1], acc[fi][fj], 0, 0, 0);
      }
    }
    __builtin_amdgcn_s_setprio(0);
    if (kt + 1 < NT) AWRITE(p ^ 1);
    __syncthreads();
    p ^= 1;
  }
#undef ALOAD
#undef AWRITE
#undef BSTAGE
#pragma unroll
  for (int fi = 0; fi < 8; ++fi) {
#pragma unroll
    for (int q = 0; q < 4; ++q) {
      long row = m0 + wr * 128 + fi * 16 + lh * 4 + q;
#pragma unroll
      for (int fj = 0; fj < 4; ++fj) {
        long col = n0 + wc * 64 + fj * 16 + l15;
        Cv[row * N + col] = f2bf(acc[fi][fj][q]);
      }
    }
  }
}

// ---------------- fused K-normrope + V-transpose (one pass over qkv K|V cols) ----------------
__global__ __launch_bounds__(256) void kv_prep(const ushort* __restrict__ QKV, // [T][2048]
                                               const float* __restrict__ kw,   // [128]
                                               const float* __restrict__ cosb, // [T][64]
                                               const float* __restrict__ sinb,
                                               ushort* __restrict__ Ka,        // [B][KV][S][128]
                                               ushort* __restrict__ Vt) {      // [B][KV][128][S]
  __shared__ ushort tile[32][33];
  const int tid = threadIdx.x, lane = tid & 63, w = tid >> 6;
  const int s0 = blockIdx.x * 32, bk = blockIdx.y;
  const int b = bk / KV_, g = bk % KV_;

  // ---- K part ----
#pragma unroll
  for (int j = 0; j < 8; ++j) {
    const int srow = s0 + w * 8 + j;
    const long t = (long)b * S_ + srow;
    const ushort* xr = QKV + t * 2048 + 1536 + g * 128;
    float x1 = bf2f(xr[lane]);
    float x2 = bf2f(xr[lane + 64]);
    float ss = x1 * x1 + x2 * x2;
#pragma unroll
    for (int off = 32; off; off >>= 1) ss += __shfl_xor(ss, off);
    float r = rsqrtf(ss * (1.0f / 128.0f) + 1e-6f);
    float y1 = x1 * r * kw[lane];
    float y2 = x2 * r * kw[lane + 64];
    float c = cosb[t * 64 + lane], s = sinb[t * 64 + lane];
    ushort* yr = Ka + ((long)bk * S_ + srow) * 128;
    yr[lane]      = f2bf(y1 * c - y2 * s);
    yr[lane + 64] = f2bf(y1 * s + y2 * c);
  }
  // ---- V part ----
  const int tx = tid & 31, ty = tid >> 5;
  for (int d0 = 0; d0 < 128; d0 += 32) {
    __syncthreads();
#pragma unroll
    for (int i = 0; i < 32; i += 8)
      tile[ty + i][tx] = QKV[(long)(b * S_ + s0 + ty + i) * 2048 + 1792 + g * 128 + d0 + tx];
    __syncthreads();
#pragma unroll
    for (int i = 0; i < 32; i += 8)
      Vt[(long)(bk * 128 + d0 + ty + i) * S_ + s0 + tx] = tile[tx][ty + i];
  }
}

// ---------------- flash attention, causal, GQA (exact r13 body: best measured, 99us) ----------------
__global__ __launch_bounds__(256, 2) void attn(ushort* __restrict__ QKV,      // [T][2048]
                                               const ushort* __restrict__ Ka, // [B][KV][S][D]
                                               const ushort* __restrict__ Vt, // [B][KV][D][S]
                                               const float* __restrict__ qnw,
                                               const float* __restrict__ cosb,
                                               const float* __restrict__ sinb) {
  __shared__ ushort lK[64 * 128];
  __shared__ ushort lV[128 * 64];
  __shared__ ushort lP[4 * 32 * 32];
  const int tid = threadIdx.x, lane = tid & 63, w = tid >> 6;
  const int l15 = lane & 15, lh = lane >> 4;
  char* cK = (char*)lK;
  char* cV = (char*)lV;
  char* cP = (char*)lP + w * 2048;
  const int swzK = l15 << 4;
  const int swzV = (l15 & 7) << 4;
  const int swzP = (l15 & 3) << 4;
  const float SCL = 0.08838834764831845f * 1.44269504088896f;  // D^-0.5 * log2(e)
  const float M0  = 17.0f;                                     // fixed softmax shift (|S|<=16.6)

  const int qt = 15 - (int)(blockIdx.x / 48);
  const int bh = blockIdx.x % 48;
  const int b = bh / H_, h = bh % H_, g = h / (H_ / KV_);
  const int q0 = qt * 128;
  const ushort* Kb = Ka + (long)(b * KV_ + g) * S_ * 128;
  const ushort* Vb = Vt + (long)(b * KV_ + g) * 128 * S_;

  // ---- Q load + in-register RMSNorm + RoPE (+ SCL prescale) ----
  bf16x8 qf[2][4];
#pragma unroll
  for (int m = 0; m < 2; ++m) {
    const long tt = (long)b * S_ + q0 + w * 32 + m * 16 + l15;
    const ushort* xr = QKV + tt * 2048 + h * 128;
    bf16x8 raw[4];
#pragma unroll
    for (int kd = 0; kd < 4; ++kd)
      raw[kd] = *(const bf16x8*)&xr[kd * 32 + lh * 8];
    float ss = 0.f;
#pragma unroll
    for (int kd = 0; kd < 4; ++kd)
#pragma unroll
      for (int e = 0; e < 8; ++e) {
        float v = bf2f((ushort)raw[kd][e]);
        ss += v * v;
      }
    ss += __shfl_xor(ss, 16);
    ss += __shfl_xor(ss, 32);
    const float rn = rsqrtf(ss * (1.0f / 128.0f) + 1e-6f) * SCL;
    const float* cR = cosb + tt * 64;
    const float* sR = sinb + tt * 64;
#pragma unroll
    for (int kp = 0; kp < 2; ++kp) {
      bf16x8 qlo, qhi;
#pragma unroll
      for (int e = 0; e < 8; ++e) {
        const int ci = kp * 32 + lh * 8 + e;
        float c = cR[ci], s = sR[ci];
        float y1 = bf2f((ushort)raw[kp][e])     * rn * qnw[ci];
        float y2 = bf2f((ushort)raw[kp + 2][e]) * rn * qnw[64 + ci];
        qlo[e] = (short)f2bf(y1 * c - y2 * s);
        qhi[e] = (short)f2bf(y1 * s + y2 * c);
      }
      qf[m][kp]     = qlo;
      qf[m][kp + 2] = qhi;
    }
  }

  f32x4 o[2][8] = {};
  float lr[2] = {0.f, 0.f};
  const int nt = 2 * qt + 2;

  bf16x8 kreg[4], vreg[4];
#define LDTILE(K0) do { \
  _Pragma("unroll") for (int it = 0; it < 4; ++it) \
    kreg[it] = *(const bf16x8*)&Kb[(long)((K0) + it * 16 + (tid >> 4)) * 128 + (tid & 15) * 8]; \
  _Pragma("unroll") for (int it = 0; it < 4; ++it) \
    vreg[it] = *(const bf16x8*)&Vb[(long)(it * 32 + (tid >> 3)) * S_ + (K0) + (tid & 7) * 8]; \
} while (0)

  LDTILE(0);
  for (int t = 0; t < nt; ++t) {
    const int k0 = t * 64;
    __syncthreads();
#pragma unroll
    for (int it = 0; it < 4; ++it) {
      int r = it * 16 + (tid >> 4);
      *(bf16x8*)(cK + r * 256 + (((tid & 15) * 16) ^ (((tid >> 4) & 15) << 4))) = kreg[it];
    }
#pragma unroll
    for (int it = 0; it < 4; ++it) {
      int r = it * 32 + (tid >> 3);
      *(bf16x8*)(cV + r * 128 + (((tid & 7) * 16) ^ ((r & 7) << 4))) = vreg[it];
    }
    __syncthreads();
    if (t + 1 < nt) LDTILE(k0 + 64);

    if (k0 <= q0 + w * 32 + 31) {
      f32x4 sfr[2][4] = {};
      __builtin_amdgcn_s_setprio(1);
#pragma unroll
      for (int kd = 0; kd < 4; ++kd) {
        bf16x8 kf[4];
#pragma unroll
        for (int n = 0; n < 4; ++n)
          kf[n] = *(const bf16x8*)(cK + (n * 16 + l15) * 256 + ((kd * 64 + lh * 16) ^ swzK));
#pragma unroll
        for (int m = 0; m < 2; ++m)
#pragma unroll
          for (int n = 0; n < 4; ++n)
            sfr[m][n] = __builtin_amdgcn_mfma_f32_16x16x32_bf16(kf[n], qf[m][kd], sfr[m][n], 0, 0, 0);
      }
      __builtin_amdgcn_s_setprio(0);
      const bool boundary = (k0 + 63 > q0 + w * 32);
      if (boundary) {
#pragma unroll
        for (int m = 0; m < 2; ++m) {
          const int rowm = q0 + w * 32 + m * 16 + l15;
#pragma unroll
          for (int n = 0; n < 4; ++n) {
            int kb = k0 + n * 16 + lh * 4;
#pragma unroll
            for (int qr = 0; qr < 4; ++qr)
              if (kb + qr > rowm) sfr[m][n][qr] = -INFINITY;
          }
        }
      }
#pragma unroll
      for (int m = 0; m < 2; ++m) {
#pragma unroll
        for (int n = 0; n < 4; ++n) {
          float p0 = exp2f(sfr[m][n][0] - M0);
          float p1 = exp2f(sfr[m][n][1] - M0);
          float p2 = exp2f(sfr[m][n][2] - M0);
          float p3 = exp2f(sfr[m][n][3] - M0);
          sfr[m][n][0] = p0; sfr[m][n][1] = p1; sfr[m][n][2] = p2; sfr[m][n][3] = p3;
          lr[m] += (p0 + p1) + (p2 + p3);
        }
      }
#pragma unroll
      for (int kf2 = 0; kf2 < 2; ++kf2) {
#pragma unroll
        for (int m = 0; m < 2; ++m)
#pragma unroll
          for (int nl = 0; nl < 2; ++nl) {
            const int n = kf2 * 2 + nl;
            uint2 pk;
            pk.x = cvtpk_bf16(sfr[m][n][0], sfr[m][n][1]);
            pk.y = cvtpk_bf16(sfr[m][n][2], sfr[m][n][3]);
            *(uint2*)(cP + (m * 16 + l15) * 64 + ((nl * 32 + lh * 8) ^ swzP)) = pk;
          }
        const int cb = (lh * 16) ^ swzP;
        bf16x8 pf0 = *(const bf16x8*)(cP + l15 * 64 + cb);
        bf16x8 pf1 = *(const bf16x8*)(cP + (16 + l15) * 64 + cb);
        const int cv = (kf2 * 64 + lh * 16);
        __builtin_amdgcn_s_setprio(1);
#pragma unroll
        for (int dblk = 0; dblk < 8; ++dblk) {
          bf16x8 vf = *(const bf16x8*)(cV + (dblk * 16 + l15) * 128 + (cv ^ swzV));
          o[0][dblk] = __builtin_amdgcn_mfma_f32_16x16x32_bf16(pf0, vf, o[0][dblk], 0, 0, 0);
          o[1][dblk] = __builtin_amdgcn_mfma_f32_16x16x32_bf16(pf1, vf, o[1][dblk], 0, 0, 0);
        }
        __builtin_amdgcn_s_setprio(0);
      }
    }
  }
#undef LDTILE
  // ---- epilogue ----
#pragma unroll
  for (int m = 0; m < 2; ++m) {
    lr[m] += __shfl_xor(lr[m], 16);
    lr[m] += __shfl_xor(lr[m], 32);
    float inv = 1.f / lr[m];
#pragma unroll
    for (int qr = 0; qr < 4; ++qr) {
      float iv = __shfl(inv, lh * 4 + qr);
      long trow = (long)b * S_ + q0 + w * 32 + m * 16 + lh * 4 + qr;
#pragma unroll
      for (int dblk = 0; dblk < 8; ++dblk)
        QKV[trow * 2048 + h * 128 + dblk * 16 + l15] = f2bf(o[m][dblk][qr] * iv);
    }
  }
}

extern "C" void kernel_launch(void* const* d_in, const int* in_sizes, int n_in,
                              void* d_out, int out_size, void* d_ws, size_t ws_size,
                              hipStream_t stream) {
  const float* hs   = (const float*)d_in[0];
  const float* cosb = (const float*)d_in[1];
  const float* sinb = (const float*)d_in[2];
  const float* Wq   = (const float*)d_in[3];
  const float* Wk   = (const float*)d_in[4];
  const float* Wv   = (const float*)d_in[5];
  const float* Wo   = (const float*)d_in[6];
  const float* qw   = (const float*)d_in[7];
  const float* kw   = (const float*)d_in[8];
  (void)in_sizes; (void)n_in; (void)out_size; (void)ws_size;

  char* ws = (char*)d_ws;
  size_t off = 0;
  auto alloc = [&](size_t bytes) {
    void* p = ws + off;
    off += (bytes + 255) & ~(size_t)255;
    return p;
  };
  ushort* Wqt = (ushort*)alloc((size_t)HID_ * HID_ * 2);  // rows 0-1535   (Wq^T)
  ushort* Wkt = (ushort*)alloc((size_t)256 * HID_ * 2);   // rows 1536-1791 (Wk^T) -- contiguous
  ushort* Wvt = (ushort*)alloc((size_t)256 * HID_ * 2);   // rows 1792-2047 (Wv^T) -- contiguous
  ushort* Wot = (ushort*)alloc((size_t)HID_ * HID_ * 2);
  ushort* qkv = (ushort*)alloc((size_t)T_ * 2048 * 2);    // fused QKV proj out; Q cols become attn O
  ushort* ka  = (ushort*)alloc((size_t)T_ * 256 * 2);
  ushort* vt  = (ushort*)alloc((size_t)T_ * 256 * 2);

  transpose_cvt2<<<dim3(HID_ / 32, HID_ / 32, 2), 256, 0, stream>>>(Wq, Wqt, Wo, Wot, HID_, HID_);
  transpose_cvt2<<<dim3(HID_ / 32, 256 / 32, 2), 256, 0, stream>>>(Wk, Wkt, Wv, Wvt, HID_, 256);

  // fused cvt + Q|K|V projection
  gemm256f<<<dim3(T_ / 256, 2048 / 256), 512, 0, stream>>>(hs, Wqt, qkv, T_, 2048, HID_, HID_);

  // fused K-normrope + V-transpose
  kv_prep<<<dim3(S_ / 32, B_ * KV_), 256, 0, stream>>>(qkv, kw, cosb, sinb, ka, vt);

  attn<<<768, 256, 0, stream>>>(qkv, ka, vt, qw, cosb, sinb);

  // O-proj on the double-buffered BK=64 kernel
  gemm_bt64<1><<<dim3(T_ / 128, 1536 / 128), 256, 0, stream>>>(qkv, Wot, (float*)d_out, T_, 1536, HID_, 2048);
}

// Round 19
// 214.086 us; speedup vs baseline: 1.0390x; 1.0390x over previous
//
#include <hip/hip_runtime.h>
#include <hip/hip_bf16.h>
#include <stdint.h>

#define H_   12
#define KV_  2
#define D_   128
#define HID_ 1536
#define B_   4
#define S_   2048
#define T_   (B_*S_)

typedef __attribute__((ext_vector_type(8))) short  bf16x8;
typedef __attribute__((ext_vector_type(4))) float  f32x4;

__device__ __forceinline__ ushort f2bf(float f) {
  union { float f; uint32_t u; } v; v.f = f;
  uint32_t u = v.u;
  return (ushort)((u + 0x7fffu + ((u >> 16) & 1u)) >> 16);  // RNE
}
__device__ __forceinline__ float bf2f(ushort u) {
  union { uint32_t u; float f; } v; v.u = ((uint32_t)u) << 16;
  return v.f;
}
__device__ __forceinline__ uint32_t cvtpk_bf16(float lo, float hi) {
  uint32_t r;
  asm("v_cvt_pk_bf16_f32 %0, %1, %2" : "=v"(r) : "v"(lo), "v"(hi));
  return r;
}

__device__ __forceinline__ void gload_lds16(const void* g, void* l) {
  __builtin_amdgcn_global_load_lds(
      (const __attribute__((address_space(1))) uint32_t*)g,
      (__attribute__((address_space(3))) uint32_t*)l, 16, 0, 0);
}

// ---------------- transpose + convert, dual-source: W (K,N) fp32 -> Wt (N,K) bf16 ----------------
__global__ __launch_bounds__(256) void transpose_cvt2(const float* __restrict__ W0,
                                                      ushort* __restrict__ Wt0,
                                                      const float* __restrict__ W1,
                                                      ushort* __restrict__ Wt1,
                                                      int K, int N) {
  __shared__ float tile[32][33];
  const float* W  = blockIdx.z ? W1  : W0;
  ushort*      Wt = blockIdx.z ? Wt1 : Wt0;
  int k0 = blockIdx.x * 32, n0 = blockIdx.y * 32;
  int tx = threadIdx.x & 31, ty = threadIdx.x >> 5;  // ty 0..7
#pragma unroll
  for (int i = 0; i < 32; i += 8)
    tile[ty + i][tx] = W[(long)(k0 + ty + i) * N + n0 + tx];
  __syncthreads();
#pragma unroll
  for (int i = 0; i < 32; i += 8)
    Wt[(long)(n0 + ty + i) * K + k0 + tx] = f2bf(tile[tx][ty + i]);
}

// ---------------- GEMM 128x128 (m97 structure): C(M,N) = A(M,K;lda) * Bt(N,K)^T ----------------
// 16KB LDS + launch_bounds(256,2) + VGPR~124 -> 4 blocks/CU; implicit cross-block wave
// overlap beats explicit dbuf at this tile (r18: 64KB dbuf halved residency, -6.6us).
template <int OUT_F32>
__global__ __launch_bounds__(256, 2) void gemm_bt(const ushort* __restrict__ A,
                                                  const ushort* __restrict__ Bt,
                                                  void* __restrict__ Cv,
                                                  int M, int N, int K, int lda) {
  __shared__ ushort lA[128 * 32];
  __shared__ ushort lB[128 * 32];
  const int tid = threadIdx.x;
  const int lane = tid & 63, w = tid >> 6;
  const int wr = w >> 1, wc = w & 1;
  const int l15 = lane & 15, lh = lane >> 4;
  const long m0 = (long)blockIdx.x * 128, n0 = (long)blockIdx.y * 128;
  const ushort* Ab = A + m0 * lda;
  const ushort* Bb = Bt + n0 * K;
  const int sr = tid >> 2;
  const int sc = (tid & 3) * 8;
  const int ldsoff = w * 512;
  f32x4 acc[4][4] = {};

  for (int k0 = 0; k0 < K; k0 += 32) {
#pragma unroll
    for (int it = 0; it < 2; ++it) {
      gload_lds16(Ab + (long)(it * 64 + sr) * lda + k0 + sc, &lA[it * 2048 + ldsoff]);
      gload_lds16(Bb + (long)(it * 64 + sr) * K + k0 + sc, &lB[it * 2048 + ldsoff]);
    }
    __syncthreads();
    bf16x8 af[4], bfr[4];
    const int ra = (wr * 64 + l15) * 32 + lh * 8;
    const int rb = (wc * 64 + l15) * 32 + lh * 8;
#pragma unroll
    for (int i = 0; i < 4; ++i) {
      af[i]  = *(const bf16x8*)&lA[ra + i * 16 * 32];
      bfr[i] = *(const bf16x8*)&lB[rb + i * 16 * 32];
    }
#pragma unroll
    for (int i = 0; i < 4; ++i)
#pragma unroll
      for (int j = 0; j < 4; ++j)
        acc[i][j] = __builtin_amdgcn_mfma_f32_16x16x32_bf16(af[i], bfr[j], acc[i][j], 0, 0, 0);
    __syncthreads();
  }
#pragma unroll
  for (int i = 0; i < 4; ++i) {
#pragma unroll
    for (int q = 0; q < 4; ++q) {
      long row = m0 + wr * 64 + i * 16 + lh * 4 + q;
#pragma unroll
      for (int j = 0; j < 4; ++j) {
        long col = n0 + wc * 64 + j * 16 + l15;
        float v = acc[i][j][q];
        if (OUT_F32) ((float*)Cv)[row * N + col] = v;
        else         ((ushort*)Cv)[row * N + col] = f2bf(v);
      }
    }
  }
}

// ------- GEMM 256x256 with FUSED fp32->bf16 A conversion (reg-staged A, gload_lds B) -------
__global__ __launch_bounds__(512) void gemm256f(const float* __restrict__ A32,
                                                const ushort* __restrict__ Bt,
                                                ushort* __restrict__ Cv,
                                                int M, int N, int K, int lda) {
  __shared__ ushort lA[2][256 * 64];
  __shared__ ushort lB[2][256 * 64];
  const int tid = threadIdx.x, lane = tid & 63;
  const int w = tid >> 6;
  const int l15 = lane & 15, lh = lane >> 4;
  const int wr = w >> 2, wc = w & 3;
  const long m0 = (long)blockIdx.x * 256, n0 = (long)blockIdx.y * 256;
  const float*  Ab = A32 + m0 * lda;
  const ushort* Bb = Bt + n0 * K;
  const int swz = (l15 & 7) << 4;

  f32x4 acc[8][4] = {};
  const int NT = K / 64;
  float4 areg[4][2];

#define ALOAD(KT) do {                                                        \
  const int k0s = (KT) * 64;                                                  \
  _Pragma("unroll") for (int it = 0; it < 4; ++it) {                          \
    int ch = it * 512 + tid; int r = ch >> 3, s = ch & 7;                     \
    const float* src = Ab + (long)r * lda + k0s + ((s ^ (r & 7)) * 8);        \
    areg[it][0] = *(const float4*)src;                                        \
    areg[it][1] = *(const float4*)(src + 4);                                  \
  }                                                                           \
} while (0)
#define AWRITE(PB) do {                                                       \
  _Pragma("unroll") for (int it = 0; it < 4; ++it) {                          \
    int ch = it * 512 + tid; int r = ch >> 3, s = ch & 7;                     \
    uint32_t pk0 = cvtpk_bf16(areg[it][0].x, areg[it][0].y);                  \
    uint32_t pk1 = cvtpk_bf16(areg[it][0].z, areg[it][0].w);                  \
    uint32_t pk2 = cvtpk_bf16(areg[it][1].x, areg[it][1].y);                  \
    uint32_t pk3 = cvtpk_bf16(areg[it][1].z, areg[it][1].w);                  \
    uint4 pk = make_uint4(pk0, pk1, pk2, pk3);                                \
    *(uint4*)&lA[PB][r * 64 + s * 8] = pk;                                    \
  }                                                                           \
} while (0)
#define BSTAGE(KT, PB) do {                                                   \
  const int k0s = (KT) * 64;                                                  \
  _Pragma("unroll") for (int it = 0; it < 4; ++it) {                          \
    int ch = it * 512 + tid; int r = ch >> 3, s = ch & 7;                     \
    int cb = it * 512 + (tid & 448);                                          \
    gload_lds16(Bb + (long)r * K + k0s + ((s ^ (r & 7)) * 8), &lB[PB][cb * 8]); \
  }                                                                           \
} while (0)

  ALOAD(0);
  BSTAGE(0, 0);
  AWRITE(0);
  __syncthreads();
  int p = 0;
  for (int kt = 0; kt < NT; ++kt) {
    if (kt + 1 < NT) { ALOAD(kt + 1); BSTAGE(kt + 1, p ^ 1); }
    const char* cA = (const char*)&lA[p][0];
    const char* cB = (const char*)&lB[p][0];
    bf16x8 bf[4][2];
#pragma unroll
    for (int fj = 0; fj < 4; ++fj)
#pragma unroll
      for (int kk = 0; kk < 2; ++kk)
        bf[fj][kk] = *(const bf16x8*)(cB + (wc * 64 + fj * 16 + l15) * 128 + ((kk * 64 + lh * 16) ^ swz));
    __builtin_amdgcn_s_setprio(1);
#pragma unroll
    for (int fi = 0; fi < 8; ++fi) {
      const int ra = (wr * 128 + fi * 16 + l15) * 128;
      bf16x8 af0 = *(const bf16x8*)(cA + ra + ((lh * 16) ^ swz));
      bf16x8 af1 = *(const bf16x8*)(cA + ra + ((64 + lh * 16) ^ swz));
#pragma unroll
      for (int fj = 0; fj < 4; ++fj) {
        acc[fi][fj] = __builtin_amdgcn_mfma_f32_16x16x32_bf16(af0, bf[fj][0], acc[fi][fj], 0, 0, 0);
        acc[fi][fj] = __builtin_amdgcn_mfma_f32_16x16x32_bf16(af1, bf[fj][1], acc[fi][fj], 0, 0, 0);
      }
    }
    __builtin_amdgcn_s_setprio(0);
    if (kt + 1 < NT) AWRITE(p ^ 1);
    __syncthreads();
    p ^= 1;
  }
#undef ALOAD
#undef AWRITE
#undef BSTAGE
#pragma unroll
  for (int fi = 0; fi < 8; ++fi) {
#pragma unroll
    for (int q = 0; q < 4; ++q) {
      long row = m0 + wr * 128 + fi * 16 + lh * 4 + q;
#pragma unroll
      for (int fj = 0; fj < 4; ++fj) {
        long col = n0 + wc * 64 + fj * 16 + l15;
        Cv[row * N + col] = f2bf(acc[fi][fj][q]);
      }
    }
  }
}

// ---------------- fused K-normrope + V-transpose (one pass over qkv K|V cols) ----------------
__global__ __launch_bounds__(256) void kv_prep(const ushort* __restrict__ QKV, // [T][2048]
                                               const float* __restrict__ kw,   // [128]
                                               const float* __restrict__ cosb, // [T][64]
                                               const float* __restrict__ sinb,
                                               ushort* __restrict__ Ka,        // [B][KV][S][128]
                                               ushort* __restrict__ Vt) {      // [B][KV][128][S]
  __shared__ ushort tile[32][33];
  const int tid = threadIdx.x, lane = tid & 63, w = tid >> 6;
  const int s0 = blockIdx.x * 32, bk = blockIdx.y;
  const int b = bk / KV_, g = bk % KV_;

  // ---- K part ----
#pragma unroll
  for (int j = 0; j < 8; ++j) {
    const int srow = s0 + w * 8 + j;
    const long t = (long)b * S_ + srow;
    const ushort* xr = QKV + t * 2048 + 1536 + g * 128;
    float x1 = bf2f(xr[lane]);
    float x2 = bf2f(xr[lane + 64]);
    float ss = x1 * x1 + x2 * x2;
#pragma unroll
    for (int off = 32; off; off >>= 1) ss += __shfl_xor(ss, off);
    float r = rsqrtf(ss * (1.0f / 128.0f) + 1e-6f);
    float y1 = x1 * r * kw[lane];
    float y2 = x2 * r * kw[lane + 64];
    float c = cosb[t * 64 + lane], s = sinb[t * 64 + lane];
    ushort* yr = Ka + ((long)bk * S_ + srow) * 128;
    yr[lane]      = f2bf(y1 * c - y2 * s);
    yr[lane + 64] = f2bf(y1 * s + y2 * c);
  }
  // ---- V part ----
  const int tx = tid & 31, ty = tid >> 5;
  for (int d0 = 0; d0 < 128; d0 += 32) {
    __syncthreads();
#pragma unroll
    for (int i = 0; i < 32; i += 8)
      tile[ty + i][tx] = QKV[(long)(b * S_ + s0 + ty + i) * 2048 + 1792 + g * 128 + d0 + tx];
    __syncthreads();
#pragma unroll
    for (int i = 0; i < 32; i += 8)
      Vt[(long)(bk * 128 + d0 + ty + i) * S_ + s0 + tx] = tile[tx][ty + i];
  }
}

// ---------------- flash attention, causal, GQA (exact r13 body: best measured, 99us) ----------------
__global__ __launch_bounds__(256, 2) void attn(ushort* __restrict__ QKV,      // [T][2048]
                                               const ushort* __restrict__ Ka, // [B][KV][S][D]
                                               const ushort* __restrict__ Vt, // [B][KV][D][S]
                                               const float* __restrict__ qnw,
                                               const float* __restrict__ cosb,
                                               const float* __restrict__ sinb) {
  __shared__ ushort lK[64 * 128];
  __shared__ ushort lV[128 * 64];
  __shared__ ushort lP[4 * 32 * 32];
  const int tid = threadIdx.x, lane = tid & 63, w = tid >> 6;
  const int l15 = lane & 15, lh = lane >> 4;
  char* cK = (char*)lK;
  char* cV = (char*)lV;
  char* cP = (char*)lP + w * 2048;
  const int swzK = l15 << 4;
  const int swzV = (l15 & 7) << 4;
  const int swzP = (l15 & 3) << 4;
  const float SCL = 0.08838834764831845f * 1.44269504088896f;  // D^-0.5 * log2(e)
  const float M0  = 17.0f;                                     // fixed softmax shift (|S|<=16.6)

  const int qt = 15 - (int)(blockIdx.x / 48);
  const int bh = blockIdx.x % 48;
  const int b = bh / H_, h = bh % H_, g = h / (H_ / KV_);
  const int q0 = qt * 128;
  const ushort* Kb = Ka + (long)(b * KV_ + g) * S_ * 128;
  const ushort* Vb = Vt + (long)(b * KV_ + g) * 128 * S_;

  // ---- Q load + in-register RMSNorm + RoPE (+ SCL prescale) ----
  bf16x8 qf[2][4];
#pragma unroll
  for (int m = 0; m < 2; ++m) {
    const long tt = (long)b * S_ + q0 + w * 32 + m * 16 + l15;
    const ushort* xr = QKV + tt * 2048 + h * 128;
    bf16x8 raw[4];
#pragma unroll
    for (int kd = 0; kd < 4; ++kd)
      raw[kd] = *(const bf16x8*)&xr[kd * 32 + lh * 8];
    float ss = 0.f;
#pragma unroll
    for (int kd = 0; kd < 4; ++kd)
#pragma unroll
      for (int e = 0; e < 8; ++e) {
        float v = bf2f((ushort)raw[kd][e]);
        ss += v * v;
      }
    ss += __shfl_xor(ss, 16);
    ss += __shfl_xor(ss, 32);
    const float rn = rsqrtf(ss * (1.0f / 128.0f) + 1e-6f) * SCL;
    const float* cR = cosb + tt * 64;
    const float* sR = sinb + tt * 64;
#pragma unroll
    for (int kp = 0; kp < 2; ++kp) {
      bf16x8 qlo, qhi;
#pragma unroll
      for (int e = 0; e < 8; ++e) {
        const int ci = kp * 32 + lh * 8 + e;
        float c = cR[ci], s = sR[ci];
        float y1 = bf2f((ushort)raw[kp][e])     * rn * qnw[ci];
        float y2 = bf2f((ushort)raw[kp + 2][e]) * rn * qnw[64 + ci];
        qlo[e] = (short)f2bf(y1 * c - y2 * s);
        qhi[e] = (short)f2bf(y1 * s + y2 * c);
      }
      qf[m][kp]     = qlo;
      qf[m][kp + 2] = qhi;
    }
  }

  f32x4 o[2][8] = {};
  float lr[2] = {0.f, 0.f};
  const int nt = 2 * qt + 2;

  bf16x8 kreg[4], vreg[4];
#define LDTILE(K0) do { \
  _Pragma("unroll") for (int it = 0; it < 4; ++it) \
    kreg[it] = *(const bf16x8*)&Kb[(long)((K0) + it * 16 + (tid >> 4)) * 128 + (tid & 15) * 8]; \
  _Pragma("unroll") for (int it = 0; it < 4; ++it) \
    vreg[it] = *(const bf16x8*)&Vb[(long)(it * 32 + (tid >> 3)) * S_ + (K0) + (tid & 7) * 8]; \
} while (0)

  LDTILE(0);
  for (int t = 0; t < nt; ++t) {
    const int k0 = t * 64;
    __syncthreads();
#pragma unroll
    for (int it = 0; it < 4; ++it) {
      int r = it * 16 + (tid >> 4);
      *(bf16x8*)(cK + r * 256 + (((tid & 15) * 16) ^ (((tid >> 4) & 15) << 4))) = kreg[it];
    }
#pragma unroll
    for (int it = 0; it < 4; ++it) {
      int r = it * 32 + (tid >> 3);
      *(bf16x8*)(cV + r * 128 + (((tid & 7) * 16) ^ ((r & 7) << 4))) = vreg[it];
    }
    __syncthreads();
    if (t + 1 < nt) LDTILE(k0 + 64);

    if (k0 <= q0 + w * 32 + 31) {
      f32x4 sfr[2][4] = {};
      __builtin_amdgcn_s_setprio(1);
#pragma unroll
      for (int kd = 0; kd < 4; ++kd) {
        bf16x8 kf[4];
#pragma unroll
        for (int n = 0; n < 4; ++n)
          kf[n] = *(const bf16x8*)(cK + (n * 16 + l15) * 256 + ((kd * 64 + lh * 16) ^ swzK));
#pragma unroll
        for (int m = 0; m < 2; ++m)
#pragma unroll
          for (int n = 0; n < 4; ++n)
            sfr[m][n] = __builtin_amdgcn_mfma_f32_16x16x32_bf16(kf[n], qf[m][kd], sfr[m][n], 0, 0, 0);
      }
      __builtin_amdgcn_s_setprio(0);
      const bool boundary = (k0 + 63 > q0 + w * 32);
      if (boundary) {
#pragma unroll
        for (int m = 0; m < 2; ++m) {
          const int rowm = q0 + w * 32 + m * 16 + l15;
#pragma unroll
          for (int n = 0; n < 4; ++n) {
            int kb = k0 + n * 16 + lh * 4;
#pragma unroll
            for (int qr = 0; qr < 4; ++qr)
              if (kb + qr > rowm) sfr[m][n][qr] = -INFINITY;
          }
        }
      }
#pragma unroll
      for (int m = 0; m < 2; ++m) {
#pragma unroll
        for (int n = 0; n < 4; ++n) {
          float p0 = exp2f(sfr[m][n][0] - M0);
          float p1 = exp2f(sfr[m][n][1] - M0);
          float p2 = exp2f(sfr[m][n][2] - M0);
          float p3 = exp2f(sfr[m][n][3] - M0);
          sfr[m][n][0] = p0; sfr[m][n][1] = p1; sfr[m][n][2] = p2; sfr[m][n][3] = p3;
          lr[m] += (p0 + p1) + (p2 + p3);
        }
      }
#pragma unroll
      for (int kf2 = 0; kf2 < 2; ++kf2) {
#pragma unroll
        for (int m = 0; m < 2; ++m)
#pragma unroll
          for (int nl = 0; nl < 2; ++nl) {
            const int n = kf2 * 2 + nl;
            uint2 pk;
            pk.x = cvtpk_bf16(sfr[m][n][0], sfr[m][n][1]);
            pk.y = cvtpk_bf16(sfr[m][n][2], sfr[m][n][3]);
            *(uint2*)(cP + (m * 16 + l15) * 64 + ((nl * 32 + lh * 8) ^ swzP)) = pk;
          }
        const int cb = (lh * 16) ^ swzP;
        bf16x8 pf0 = *(const bf16x8*)(cP + l15 * 64 + cb);
        bf16x8 pf1 = *(const bf16x8*)(cP + (16 + l15) * 64 + cb);
        const int cv = (kf2 * 64 + lh * 16);
        __builtin_amdgcn_s_setprio(1);
#pragma unroll
        for (int dblk = 0; dblk < 8; ++dblk) {
          bf16x8 vf = *(const bf16x8*)(cV + (dblk * 16 + l15) * 128 + (cv ^ swzV));
          o[0][dblk] = __builtin_amdgcn_mfma_f32_16x16x32_bf16(pf0, vf, o[0][dblk], 0, 0, 0);
          o[1][dblk] = __builtin_amdgcn_mfma_f32_16x16x32_bf16(pf1, vf, o[1][dblk], 0, 0, 0);
        }
        __builtin_amdgcn_s_setprio(0);
      }
    }
  }
#undef LDTILE
  // ---- epilogue ----
#pragma unroll
  for (int m = 0; m < 2; ++m) {
    lr[m] += __shfl_xor(lr[m], 16);
    lr[m] += __shfl_xor(lr[m], 32);
    float inv = 1.f / lr[m];
#pragma unroll
    for (int qr = 0; qr < 4; ++qr) {
      float iv = __shfl(inv, lh * 4 + qr);
      long trow = (long)b * S_ + q0 + w * 32 + m * 16 + lh * 4 + qr;
#pragma unroll
      for (int dblk = 0; dblk < 8; ++dblk)
        QKV[trow * 2048 + h * 128 + dblk * 16 + l15] = f2bf(o[m][dblk][qr] * iv);
    }
  }
}

extern "C" void kernel_launch(void* const* d_in, const int* in_sizes, int n_in,
                              void* d_out, int out_size, void* d_ws, size_t ws_size,
                              hipStream_t stream) {
  const float* hs   = (const float*)d_in[0];
  const float* cosb = (const float*)d_in[1];
  const float* sinb = (const float*)d_in[2];
  const float* Wq   = (const float*)d_in[3];
  const float* Wk   = (const float*)d_in[4];
  const float* Wv   = (const float*)d_in[5];
  const float* Wo   = (const float*)d_in[6];
  const float* qw   = (const float*)d_in[7];
  const float* kw   = (const float*)d_in[8];
  (void)in_sizes; (void)n_in; (void)out_size; (void)ws_size;

  char* ws = (char*)d_ws;
  size_t off = 0;
  auto alloc = [&](size_t bytes) {
    void* p = ws + off;
    off += (bytes + 255) & ~(size_t)255;
    return p;
  };
  ushort* Wqt = (ushort*)alloc((size_t)HID_ * HID_ * 2);  // rows 0-1535   (Wq^T)
  ushort* Wkt = (ushort*)alloc((size_t)256 * HID_ * 2);   // rows 1536-1791 (Wk^T) -- contiguous
  ushort* Wvt = (ushort*)alloc((size_t)256 * HID_ * 2);   // rows 1792-2047 (Wv^T) -- contiguous
  ushort* Wot = (ushort*)alloc((size_t)HID_ * HID_ * 2);
  ushort* qkv = (ushort*)alloc((size_t)T_ * 2048 * 2);    // fused QKV proj out; Q cols become attn O
  ushort* ka  = (ushort*)alloc((size_t)T_ * 256 * 2);
  ushort* vt  = (ushort*)alloc((size_t)T_ * 256 * 2);

  transpose_cvt2<<<dim3(HID_ / 32, HID_ / 32, 2), 256, 0, stream>>>(Wq, Wqt, Wo, Wot, HID_, HID_);
  transpose_cvt2<<<dim3(HID_ / 32, 256 / 32, 2), 256, 0, stream>>>(Wk, Wkt, Wv, Wvt, HID_, 256);

  // fused cvt + Q|K|V projection
  gemm256f<<<dim3(T_ / 256, 2048 / 256), 512, 0, stream>>>(hs, Wqt, qkv, T_, 2048, HID_, HID_);

  // fused K-normrope + V-transpose
  kv_prep<<<dim3(S_ / 32, B_ * KV_), 256, 0, stream>>>(qkv, kw, cosb, sinb, ka, vt);

  attn<<<768, 256, 0, stream>>>(qkv, ka, vt, qw, cosb, sinb);

  // O-proj on the m97 128^2 kernel (4 blocks/CU; best measured for this shape)
  gemm_bt<1><<<dim3(T_ / 128, 1536 / 128), 256, 0, stream>>>(qkv, Wot, (float*)d_out, T_, 1536, HID_, 2048);
}